// Round 13
// baseline (137.762 us; speedup 1.0000x reference)
//
#include <hip/hip_runtime.h>
#include <math.h>

// Problem constants
#define NXg 48
#define NYg 48
#define Tg 512
#define NG 20000              // B*NE, batch folded
#define H1g 64
#define H2g 128

// Tiling
#define TT 32                 // ticks per bin
#define NBINS 16
#define RCAP 3072             // per-bin list capacity (max count ~2650)
#define CCAP (RCAP / 32)      // 96 K-chunks max per bin
#define NSB 18                // sensor blocks of 128 (18*128 = 2304)

// coordinate pre-scale: exp(-0.5*d2/es^2) = exp2(-(k*d)^2), k = sqrt(0.5*log2 e)/es
#define KSCALE 0.84932180028802f

typedef float vf16 __attribute__((ext_vector_type(16)));
typedef _Float16 half8 __attribute__((ext_vector_type(8)));
typedef float floatx4 __attribute__((ext_vector_type(4)));

// ws layout (bytes)
#define OFF_BFRAG  0                                     // 6,291,456
#define OFF_POSC   (OFF_BFRAG  + (size_t)NBINS*CCAP*4*512*2)
#define OFF_EDATA2 (OFF_POSC   + (size_t)NBINS*RCAP*8)   //   393,216
#define OFF_LIST   (OFF_EDATA2 + (size_t)NG*16)          //   320,000
#define OFF_CNT    (OFF_LIST   + (size_t)NBINS*RCAP*4)   //   196,608
// total ~7.2 MB

// ---------------------------------------------------------------------------
// Kernel 1: fused MLP + amp fold + binning. 8 threads per electron (each
// handles 16 H2 columns), W2 staged in LDS (32 KB), shfl_xor reduce within
// the aligned 8-thread group. Leader thread computes amp, writes edata2
// (pre-scaled coords), and does the two-phase LDS-histogram binning.
// Grid: 625 blocks x 256 threads = 20000 electrons exactly.
// ---------------------------------------------------------------------------
__global__ __launch_bounds__(256) void k_fused(
    const float* __restrict__ sim, const float* __restrict__ zpos,
    const float* __restrict__ mask,
    const float* __restrict__ W1, const float* __restrict__ b1,
    const float* __restrict__ W2, const float* __restrict__ b2,
    const float* __restrict__ W3, const float* __restrict__ b3,
    const float* __restrict__ el_spread,
    float4* __restrict__ edata2, int* __restrict__ cnt, int* __restrict__ list)
{
    __shared__ __align__(16) float sW2[H1g][H2g];   // 32 KB
    __shared__ float4 sW1b[H1g];                    // {W1[j], W1[64+j], b1[j], 0}
    __shared__ int lcnt[NBINS], lbase[NBINS];

    int tid = threadIdx.x;
    if (tid < H1g)
        sW1b[tid] = make_float4(W1[tid], W1[H1g + tid], b1[tid], 0.0f);
    if (tid < NBINS) lcnt[tid] = 0;
    {
        float4* d = (float4*)&sW2[0][0];
        const float4* s = (const float4*)W2;
        for (int i = tid; i < H1g * H2g / 4; i += 256) d[i] = s[i];
    }
    __syncthreads();

    int sub = tid & 7;
    int g = blockIdx.x * 32 + (tid >> 3);        // always < NG (625*32 = 20000)
    int k0 = sub * 16;

    float2 s0 = *(const float2*)&sim[2 * g];

    vf16 a = *(const vf16*)&b2[k0];
#pragma unroll 4
    for (int j = 0; j < H1g; ++j) {
        float4 wb = sW1b[j];                     // LDS broadcast
        float h = fmaxf(fmaf(s0.x, wb.x, fmaf(s0.y, wb.y, wb.z)), 0.0f);
        vf16 w = *(const vf16*)&sW2[j][k0];      // 64B LDS, 8 distinct addrs
#pragma unroll
        for (int u = 0; u < 16; ++u) a[u] = fmaf(h, w[u], a[u]);
    }
    float r = (sub == 0) ? b3[0] : 0.0f;
#pragma unroll
    for (int u = 0; u < 16; ++u)
        r = fmaf(fmaxf(a[u], 0.0f), W3[k0 + u], r);
    r += __shfl_xor(r, 1);
    r += __shfl_xor(r, 2);
    r += __shfl_xor(r, 4);                       // full resp in all 8 lanes

    int jlo = 0, jhi = -1;
    int off[3];
    if (sub == 0) {
        float z = zpos[g];
        float es = el_spread[0];
        float amp = r * mask[g] * (100.0f / (es * 2.5066f)) *
                    (0.3989422804f / 2.23606797749979f);
        float kk = KSCALE / es;
        edata2[g] = make_float4(s0.x * kk, s0.y * kk, z, amp);
        // bins with min |t-z| <= sqrt(180): dropped time terms < e^-18
        jlo = max((int)ceilf((z - 44.5f) * (1.0f / 32.0f)), 0);
        jhi = min((int)floorf((z + 13.5f) * (1.0f / 32.0f)), NBINS - 1);
        for (int j = jlo; j <= jhi; ++j)
            off[j - jlo] = atomicAdd(&lcnt[j], 1);
    }
    __syncthreads();
    if (tid < NBINS) {
        int c = lcnt[tid];
        lbase[tid] = c ? atomicAdd(&cnt[tid], c) : 0;
    }
    __syncthreads();
    if (sub == 0) {
        for (int j = jlo; j <= jhi; ++j) {
            int p = lbase[j] + off[j - jlo];
            if (p < RCAP) list[j * RCAP + p] = g;
        }
    }
}

// ---------------------------------------------------------------------------
// Kernel 2: B-fragment build, coalesced (two contiguous 16B stores/thread).
// (unchanged structure — verified R7..R12)
// ---------------------------------------------------------------------------
__global__ __launch_bounds__(256) void k_prof(
    const float4* __restrict__ edata2, const int* __restrict__ cnt,
    const int* __restrict__ list,
    _Float16* __restrict__ bfrag, float2* __restrict__ posc)
{
    __shared__ float4 sE[64];
    int bin = blockIdx.y;
    int tid = threadIdx.x;
    int count = min(cnt[bin], RCAP);
    int nch = (count + 31) >> 5;
    int cbase = blockIdx.x * 2;              // 2 chunks per block
    if (cbase >= nch) return;

    if (tid < 64) {
        int i = cbase * 32 + tid;            // entry index within bin
        float4 E = make_float4(1.0e3f, 1.0e3f, 0.0f, 0.0f);  // pad: amp=0, far
        if (i < count) E = edata2[list[bin * RCAP + i]];
        sE[tid] = E;
        if (i < nch * 32)
            posc[(size_t)bin * RCAP + i] = make_float2(E.x, E.y);
    }
    __syncthreads();

    int ch = cbase + (tid >> 7);
    if (ch >= nch) return;
    int nt = (tid >> 6) & 1;
    int lane = tid & 63;
    int quad = lane >> 4, t16 = lane & 15;
    float tt = (float)(bin * TT + nt * 16 + t16);

    half8 hi, lo;
#pragma unroll
    for (int j = 0; j < 8; ++j) {
        float4 E = sE[(tid >> 7) * 32 + quad * 8 + j];   // LDS broadcast
        float d = tt - E.z;
        float v = E.w * __expf(-0.1f * d * d);
        _Float16 h = (_Float16)v;
        hi[j] = h;
        lo[j] = (_Float16)(v - (float)h);
    }
    size_t base = ((size_t)(bin * CCAP + ch)) * 4 * 512;  // f16 units
    *(half8*)&bfrag[base + (size_t)nt * 512 + lane * 8] = hi;
    *(half8*)&bfrag[base + (size_t)(2 + nt) * 512 + lane * 8] = lo;
}

// ---------------------------------------------------------------------------
// Kernel 3: MFMA main loop, SPLIT=1, direct output write (no partials, no
// reduce kernel). M=32 per wave; positions in LDS; unroll-2 register double
// buffer on bfrag loads. A as plain f16 (ah), B split hi+lo: D += ah*(Bh+Bl)
// -> 8 MFMAs/chunk, ~30% less VALU than the hi/lo-A version.
// Grid (18, 16); block = 4 waves x 32 sensors = 128 sensors.
// ---------------------------------------------------------------------------
__global__ __launch_bounds__(256) void k_main(
    const _Float16* __restrict__ bfrag, const float2* __restrict__ posc,
    const int* __restrict__ cnt, const float* __restrict__ el_spread,
    const float* __restrict__ sensors, float* __restrict__ out)
{
    __shared__ float4 sPos[CCAP * 16];     // 96 chunks x 16 float4 = 24 KB max

    int tid = threadIdx.x;
    int wv = tid >> 6, lane = tid & 63;
    int sb = blockIdx.x, bin = blockIdx.y;
    int quad = lane >> 4;

    int count = min(cnt[bin], RCAP);
    int nch = (count + 31) >> 5;

    // stage the bin's positions into LDS: nch chunks x 16 float4
    {
        const float4* psrc = (const float4*)(posc + (size_t)bin * RCAP);
        for (int i = tid; i < nch * 16; i += 256) sPos[i] = psrc[i];
    }
    __syncthreads();

    int sA = sb * 128 + wv * 32 + (lane & 15);
    float es = el_spread[0];
    float kk = KSCALE / es;
    float sx0 = sensors[2 * sA] * kk,        sy0 = sensors[2 * sA + 1] * kk;
    float sx1 = sensors[2 * (sA + 16)] * kk, sy1 = sensors[2 * (sA + 16) + 1] * kk;

    floatx4 d00 = {0.f,0.f,0.f,0.f}, d01 = {0.f,0.f,0.f,0.f};
    floatx4 d10 = {0.f,0.f,0.f,0.f}, d11 = {0.f,0.f,0.f,0.f};

    const half8* bbase = (const half8*)bfrag + (size_t)bin * CCAP * 256 + lane;
    const float4* lbase = sPos + quad * 4;   // + c*16, then 4 consecutive

#define LOADC(c, F0, F1, F2, F3, Q0, Q1, Q2, Q3)                          \
    {                                                                     \
        const half8* bb = bbase + (size_t)(c) * 256;                      \
        F0 = bb[0]; F1 = bb[64]; F2 = bb[128]; F3 = bb[192];              \
        const float4* lp = lbase + (c) * 16;                              \
        Q0 = lp[0]; Q1 = lp[1]; Q2 = lp[2]; Q3 = lp[3];                   \
    }

#define COMP(F0, F1, F2, F3, Q0, Q1, Q2, Q3)                              \
    {                                                                     \
        float exs[8] = {Q0.x, Q0.z, Q1.x, Q1.z, Q2.x, Q2.z, Q3.x, Q3.z};  \
        float eys[8] = {Q0.y, Q0.w, Q1.y, Q1.w, Q2.y, Q2.w, Q3.y, Q3.w};  \
        half8 ah0, ah1;                                                   \
        _Pragma("unroll")                                                 \
        for (int j = 0; j < 8; ++j) {                                     \
            float dx0 = sx0 - exs[j], dy0 = sy0 - eys[j];                 \
            float dx1 = sx1 - exs[j], dy1 = sy1 - eys[j];                 \
            float e0 = __builtin_amdgcn_exp2f(-fmaf(dy0, dy0, dx0 * dx0));\
            float e1 = __builtin_amdgcn_exp2f(-fmaf(dy1, dy1, dx1 * dx1));\
            ah0[j] = (_Float16)e0;                                        \
            ah1[j] = (_Float16)e1;                                        \
        }                                                                 \
        d00 = __builtin_amdgcn_mfma_f32_16x16x32_f16(ah0, F0, d00, 0,0,0);\
        d01 = __builtin_amdgcn_mfma_f32_16x16x32_f16(ah0, F1, d01, 0,0,0);\
        d10 = __builtin_amdgcn_mfma_f32_16x16x32_f16(ah1, F0, d10, 0,0,0);\
        d11 = __builtin_amdgcn_mfma_f32_16x16x32_f16(ah1, F1, d11, 0,0,0);\
        d00 = __builtin_amdgcn_mfma_f32_16x16x32_f16(ah0, F2, d00, 0,0,0);\
        d01 = __builtin_amdgcn_mfma_f32_16x16x32_f16(ah0, F3, d01, 0,0,0);\
        d10 = __builtin_amdgcn_mfma_f32_16x16x32_f16(ah1, F2, d10, 0,0,0);\
        d11 = __builtin_amdgcn_mfma_f32_16x16x32_f16(ah1, F3, d11, 0,0,0);\
    }

    if (nch > 0) {
        half8 fA0, fA1, fA2, fA3, fB0, fB1, fB2, fB3;
        float4 qA0, qA1, qA2, qA3, qB0, qB1, qB2, qB3;
        LOADC(0, fA0, fA1, fA2, fA3, qA0, qA1, qA2, qA3);
        int c = 0;
        for (; c + 1 < nch; c += 2) {
            LOADC(c + 1, fB0, fB1, fB2, fB3, qB0, qB1, qB2, qB3);
            COMP(fA0, fA1, fA2, fA3, qA0, qA1, qA2, qA3);
            int cn = (c + 2 < nch) ? c + 2 : nch - 1;
            LOADC(cn, fA0, fA1, fA2, fA3, qA0, qA1, qA2, qA3);
            COMP(fB0, fB1, fB2, fB3, qB0, qB1, qB2, qB3);
        }
        if (c < nch) COMP(fA0, fA1, fA2, fA3, qA0, qA1, qA2, qA3);
    }
#undef LOADC
#undef COMP

    // D layout per tile: row m = quad*4 + r, col n = lane&15.
    // out[sensor][t]: sensor = sb*128 + wv*32 + quad*4 + r (+16 for tile 1),
    // t = bin*32 + {n0, 16+n0}.
    int n0 = lane & 15;
    int s0r = sb * 128 + wv * 32 + quad * 4;
#pragma unroll
    for (int r = 0; r < 4; ++r) {
        float* o0 = out + (size_t)(s0r + r) * Tg + bin * TT;
        o0[n0]      = d00[r];
        o0[16 + n0] = d01[r];
        float* o1 = o0 + 16 * Tg;
        o1[n0]      = d10[r];
        o1[16 + n0] = d11[r];
    }
}

// ---------------------------------------------------------------------------
extern "C" void kernel_launch(void* const* d_in, const int* in_sizes, int n_in,
                              void* d_out, int out_size, void* d_ws, size_t ws_size,
                              hipStream_t stream)
{
    const float* sim       = (const float*)d_in[0];
    const float* zpos      = (const float*)d_in[1];
    const float* mask      = (const float*)d_in[2];
    const float* W1        = (const float*)d_in[3];
    const float* b1        = (const float*)d_in[4];
    const float* W2        = (const float*)d_in[5];
    const float* b2        = (const float*)d_in[6];
    const float* W3        = (const float*)d_in[7];
    const float* b3        = (const float*)d_in[8];
    const float* el_spread = (const float*)d_in[9];
    const float* sensors   = (const float*)d_in[10];
    float* out = (float*)d_out;

    char* ws = (char*)d_ws;
    _Float16* bfrag  = (_Float16*)(ws + OFF_BFRAG);
    float2*   posc   = (float2*)(ws + OFF_POSC);
    float4*   edata2 = (float4*)(ws + OFF_EDATA2);
    int*      list   = (int*)(ws + OFF_LIST);
    int*      cnt    = (int*)(ws + OFF_CNT);

    hipMemsetAsync(cnt, 0, NBINS * sizeof(int), stream);

    k_fused<<<NG / 32, 256, 0, stream>>>(
        sim, zpos, mask, W1, b1, W2, b2, W3, b3, el_spread,
        edata2, cnt, list);

    k_prof<<<dim3(CCAP / 2, NBINS), 256, 0, stream>>>(
        edata2, cnt, list, bfrag, posc);

    k_main<<<dim3(NSB, NBINS), 256, 0, stream>>>(
        bfrag, posc, cnt, el_spread, sensors, out);
}

// Round 14
// 129.618 us; speedup vs baseline: 1.0628x; 1.0628x over previous
//
#include <hip/hip_runtime.h>
#include <math.h>

// Problem constants
#define NXg 48
#define NYg 48
#define Tg 512
#define NG 20000              // B*NE, batch folded
#define H1g 64
#define H2g 128

// Tiling
#define TT 32                 // ticks per bin
#define NBINS 16
#define RCAP 3072             // per-bin list capacity (max count ~2650)
#define CCAP (RCAP / 32)      // 96 K-chunks max per bin
#define SPLIT 3               // split-K over chunks (864 blocks -> ~3.4/CU)
#define NSB 18                // sensor blocks of 128 (18*128 = 2304)

// coordinate pre-scale: exp(-0.5*d2/es^2) = exp2(-(k*d)^2), k = sqrt(0.5*log2 e)/es
#define KSCALE 0.84932180028802f

typedef float vf16 __attribute__((ext_vector_type(16)));
typedef _Float16 half8 __attribute__((ext_vector_type(8)));
typedef float floatx4 __attribute__((ext_vector_type(4)));

// ws layout (bytes)
#define OFF_BFRAG  0                                     // 6,291,456
#define OFF_POSC   (OFF_BFRAG  + (size_t)NBINS*CCAP*4*512*2)
#define OFF_PART   (OFF_POSC   + (size_t)NBINS*RCAP*8)   // 14,155,776
#define OFF_EDATA2 (OFF_PART   + (size_t)SPLIT*NSB*NBINS*4096*4)
#define OFF_LIST   (OFF_EDATA2 + (size_t)NG*16)
#define OFF_CNT    (OFF_LIST   + (size_t)NBINS*RCAP*4)
// total ~21.5 MB

// ---------------------------------------------------------------------------
// Kernel 1: fused MLP + amp fold + binning (verified R13). 8 threads per
// electron, W2 in LDS, shfl_xor reduce, two-phase LDS-histogram binning.
// ---------------------------------------------------------------------------
__global__ __launch_bounds__(256) void k_fused(
    const float* __restrict__ sim, const float* __restrict__ zpos,
    const float* __restrict__ mask,
    const float* __restrict__ W1, const float* __restrict__ b1,
    const float* __restrict__ W2, const float* __restrict__ b2,
    const float* __restrict__ W3, const float* __restrict__ b3,
    const float* __restrict__ el_spread,
    float4* __restrict__ edata2, int* __restrict__ cnt, int* __restrict__ list)
{
    __shared__ __align__(16) float sW2[H1g][H2g];   // 32 KB
    __shared__ float4 sW1b[H1g];
    __shared__ int lcnt[NBINS], lbase[NBINS];

    int tid = threadIdx.x;
    if (tid < H1g)
        sW1b[tid] = make_float4(W1[tid], W1[H1g + tid], b1[tid], 0.0f);
    if (tid < NBINS) lcnt[tid] = 0;
    {
        float4* d = (float4*)&sW2[0][0];
        const float4* s = (const float4*)W2;
        for (int i = tid; i < H1g * H2g / 4; i += 256) d[i] = s[i];
    }
    __syncthreads();

    int sub = tid & 7;
    int g = blockIdx.x * 32 + (tid >> 3);        // 625*32 = 20000 exactly
    int k0 = sub * 16;

    float2 s0 = *(const float2*)&sim[2 * g];

    vf16 a = *(const vf16*)&b2[k0];
#pragma unroll 4
    for (int j = 0; j < H1g; ++j) {
        float4 wb = sW1b[j];
        float h = fmaxf(fmaf(s0.x, wb.x, fmaf(s0.y, wb.y, wb.z)), 0.0f);
        vf16 w = *(const vf16*)&sW2[j][k0];
#pragma unroll
        for (int u = 0; u < 16; ++u) a[u] = fmaf(h, w[u], a[u]);
    }
    float r = (sub == 0) ? b3[0] : 0.0f;
#pragma unroll
    for (int u = 0; u < 16; ++u)
        r = fmaf(fmaxf(a[u], 0.0f), W3[k0 + u], r);
    r += __shfl_xor(r, 1);
    r += __shfl_xor(r, 2);
    r += __shfl_xor(r, 4);

    int jlo = 0, jhi = -1;
    int off[3];
    if (sub == 0) {
        float z = zpos[g];
        float es = el_spread[0];
        float amp = r * mask[g] * (100.0f / (es * 2.5066f)) *
                    (0.3989422804f / 2.23606797749979f);
        float kk = KSCALE / es;
        edata2[g] = make_float4(s0.x * kk, s0.y * kk, z, amp);
        // bins with min |t-z| <= sqrt(180): dropped time terms < e^-18
        jlo = max((int)ceilf((z - 44.5f) * (1.0f / 32.0f)), 0);
        jhi = min((int)floorf((z + 13.5f) * (1.0f / 32.0f)), NBINS - 1);
        for (int j = jlo; j <= jhi; ++j)
            off[j - jlo] = atomicAdd(&lcnt[j], 1);
    }
    __syncthreads();
    if (tid < NBINS) {
        int c = lcnt[tid];
        lbase[tid] = c ? atomicAdd(&cnt[tid], c) : 0;
    }
    __syncthreads();
    if (sub == 0) {
        for (int j = jlo; j <= jhi; ++j) {
            int p = lbase[j] + off[j - jlo];
            if (p < RCAP) list[j * RCAP + p] = g;
        }
    }
}

// ---------------------------------------------------------------------------
// Kernel 2: B-fragment build, coalesced. (verified R7..R13)
// ---------------------------------------------------------------------------
__global__ __launch_bounds__(256) void k_prof(
    const float4* __restrict__ edata2, const int* __restrict__ cnt,
    const int* __restrict__ list,
    _Float16* __restrict__ bfrag, float2* __restrict__ posc)
{
    __shared__ float4 sE[64];
    int bin = blockIdx.y;
    int tid = threadIdx.x;
    int count = min(cnt[bin], RCAP);
    int nch = (count + 31) >> 5;
    int cbase = blockIdx.x * 2;
    if (cbase >= nch) return;

    if (tid < 64) {
        int i = cbase * 32 + tid;
        float4 E = make_float4(1.0e3f, 1.0e3f, 0.0f, 0.0f);  // pad: amp=0, far
        if (i < count) E = edata2[list[bin * RCAP + i]];
        sE[tid] = E;
        if (i < nch * 32)
            posc[(size_t)bin * RCAP + i] = make_float2(E.x, E.y);
    }
    __syncthreads();

    int ch = cbase + (tid >> 7);
    if (ch >= nch) return;
    int nt = (tid >> 6) & 1;
    int lane = tid & 63;
    int quad = lane >> 4, t16 = lane & 15;
    float tt = (float)(bin * TT + nt * 16 + t16);

    half8 hi, lo;
#pragma unroll
    for (int j = 0; j < 8; ++j) {
        float4 E = sE[(tid >> 7) * 32 + quad * 8 + j];
        float d = tt - E.z;
        float v = E.w * __expf(-0.1f * d * d);
        _Float16 h = (_Float16)v;
        hi[j] = h;
        lo[j] = (_Float16)(v - (float)h);
    }
    size_t base = ((size_t)(bin * CCAP + ch)) * 4 * 512;
    *(half8*)&bfrag[base + (size_t)nt * 512 + lane * 8] = hi;
    *(half8*)&bfrag[base + (size_t)(2 + nt) * 512 + lane * 8] = lo;
}

// ---------------------------------------------------------------------------
// Kernel 3: MFMA main loop — R12's verified SPLIT=3 structure + R13's
// lighter 8-MFMA COMP (A plain f16, B hi+lo). M=32/wave, positions in LDS,
// unroll-2 register double buffer. Grid (18, 16, SPLIT).
// ---------------------------------------------------------------------------
__global__ __launch_bounds__(256) void k_main(
    const _Float16* __restrict__ bfrag, const float2* __restrict__ posc,
    const int* __restrict__ cnt, const float* __restrict__ el_spread,
    const float* __restrict__ sensors, float* __restrict__ part)
{
    __shared__ float4 sPos[512];           // 32 chunks x 16 float4 = 8 KB max

    int tid = threadIdx.x;
    int wv = tid >> 6, lane = tid & 63;
    int sb = blockIdx.x, bin = blockIdx.y, split = blockIdx.z;
    int quad = lane >> 4;

    int count = min(cnt[bin], RCAP);
    int nch = (count + 31) >> 5;
    int c0 = nch * split / SPLIT, c1 = nch * (split + 1) / SPLIT;
    int nc = c1 - c0;

    {
        const float4* psrc = (const float4*)(posc + (size_t)bin * RCAP + c0 * 32);
        for (int i = tid; i < nc * 16; i += 256) sPos[i] = psrc[i];
    }
    __syncthreads();

    int sA = sb * 128 + wv * 32 + (lane & 15);
    float es = el_spread[0];
    float kk = KSCALE / es;
    float sx0 = sensors[2 * sA] * kk,        sy0 = sensors[2 * sA + 1] * kk;
    float sx1 = sensors[2 * (sA + 16)] * kk, sy1 = sensors[2 * (sA + 16) + 1] * kk;

    floatx4 d00 = {0.f,0.f,0.f,0.f}, d01 = {0.f,0.f,0.f,0.f};
    floatx4 d10 = {0.f,0.f,0.f,0.f}, d11 = {0.f,0.f,0.f,0.f};

    const half8* bbase = (const half8*)bfrag + (size_t)bin * CCAP * 256 + lane;
    const float4* lbase = sPos + quad * 4;   // + (c-c0)*16, then 4 consecutive

#define LOADC(c, F0, F1, F2, F3, Q0, Q1, Q2, Q3)                          \
    {                                                                     \
        const half8* bb = bbase + (size_t)(c) * 256;                      \
        F0 = bb[0]; F1 = bb[64]; F2 = bb[128]; F3 = bb[192];              \
        const float4* lp = lbase + ((c) - c0) * 16;                       \
        Q0 = lp[0]; Q1 = lp[1]; Q2 = lp[2]; Q3 = lp[3];                   \
    }

#define COMP(F0, F1, F2, F3, Q0, Q1, Q2, Q3)                              \
    {                                                                     \
        float exs[8] = {Q0.x, Q0.z, Q1.x, Q1.z, Q2.x, Q2.z, Q3.x, Q3.z};  \
        float eys[8] = {Q0.y, Q0.w, Q1.y, Q1.w, Q2.y, Q2.w, Q3.y, Q3.w};  \
        half8 ah0, ah1;                                                   \
        _Pragma("unroll")                                                 \
        for (int j = 0; j < 8; ++j) {                                     \
            float dx0 = sx0 - exs[j], dy0 = sy0 - eys[j];                 \
            float dx1 = sx1 - exs[j], dy1 = sy1 - eys[j];                 \
            float e0 = __builtin_amdgcn_exp2f(-fmaf(dy0, dy0, dx0 * dx0));\
            float e1 = __builtin_amdgcn_exp2f(-fmaf(dy1, dy1, dx1 * dx1));\
            ah0[j] = (_Float16)e0;                                        \
            ah1[j] = (_Float16)e1;                                        \
        }                                                                 \
        d00 = __builtin_amdgcn_mfma_f32_16x16x32_f16(ah0, F0, d00, 0,0,0);\
        d01 = __builtin_amdgcn_mfma_f32_16x16x32_f16(ah0, F1, d01, 0,0,0);\
        d10 = __builtin_amdgcn_mfma_f32_16x16x32_f16(ah1, F0, d10, 0,0,0);\
        d11 = __builtin_amdgcn_mfma_f32_16x16x32_f16(ah1, F1, d11, 0,0,0);\
        d00 = __builtin_amdgcn_mfma_f32_16x16x32_f16(ah0, F2, d00, 0,0,0);\
        d01 = __builtin_amdgcn_mfma_f32_16x16x32_f16(ah0, F3, d01, 0,0,0);\
        d10 = __builtin_amdgcn_mfma_f32_16x16x32_f16(ah1, F2, d10, 0,0,0);\
        d11 = __builtin_amdgcn_mfma_f32_16x16x32_f16(ah1, F3, d11, 0,0,0);\
    }

    if (c0 < c1) {
        half8 fA0, fA1, fA2, fA3, fB0, fB1, fB2, fB3;
        float4 qA0, qA1, qA2, qA3, qB0, qB1, qB2, qB3;
        LOADC(c0, fA0, fA1, fA2, fA3, qA0, qA1, qA2, qA3);
        int c = c0;
        for (; c + 1 < c1; c += 2) {
            LOADC(c + 1, fB0, fB1, fB2, fB3, qB0, qB1, qB2, qB3);
            COMP(fA0, fA1, fA2, fA3, qA0, qA1, qA2, qA3);
            int cn = (c + 2 < c1) ? c + 2 : c1 - 1;
            LOADC(cn, fA0, fA1, fA2, fA3, qA0, qA1, qA2, qA3);
            COMP(fB0, fB1, fB2, fB3, qB0, qB1, qB2, qB3);
        }
        if (c < c1) COMP(fA0, fA1, fA2, fA3, qA0, qA1, qA2, qA3);
    }
#undef LOADC
#undef COMP

    float* pb = part + (((size_t)split * NSB + sb) * NBINS + bin) * 4096;
    int n0 = lane & 15;
#pragma unroll
    for (int r = 0; r < 4; ++r) {
        int sl0 = wv * 32 + quad * 4 + r;        // M-tile 0
        int sl1 = sl0 + 16;                      // M-tile 1
        pb[sl0 * 32 + n0]      = d00[r];
        pb[sl0 * 32 + 16 + n0] = d01[r];
        pb[sl1 * 32 + n0]      = d10[r];
        pb[sl1 * 32 + 16 + n0] = d11[r];
    }
}

// ---------------------------------------------------------------------------
// Kernel 4: reduce split-K partials into output. (verified R12)
// ---------------------------------------------------------------------------
__global__ __launch_bounds__(256) void k_reduce(
    const float4* __restrict__ part, float* __restrict__ out)
{
    int sb = blockIdx.x, bin = blockIdx.y, tid = threadIdx.x;
#pragma unroll
    for (int h = 0; h < 4; ++h) {
        int p = h * 256 + tid;            // float4 index within 1024
        int sl = p >> 3, q = p & 7;
        float4 s = make_float4(0.f, 0.f, 0.f, 0.f);
        for (int sp = 0; sp < SPLIT; ++sp) {
            float4 v = part[(((size_t)sp * NSB + sb) * NBINS + bin) * 1024 + p];
            s.x += v.x; s.y += v.y; s.z += v.z; s.w += v.w;
        }
        int sensor = sb * 128 + sl;
        *(float4*)(out + (size_t)sensor * Tg + bin * TT + q * 4) = s;
    }
}

// ---------------------------------------------------------------------------
extern "C" void kernel_launch(void* const* d_in, const int* in_sizes, int n_in,
                              void* d_out, int out_size, void* d_ws, size_t ws_size,
                              hipStream_t stream)
{
    const float* sim       = (const float*)d_in[0];
    const float* zpos      = (const float*)d_in[1];
    const float* mask      = (const float*)d_in[2];
    const float* W1        = (const float*)d_in[3];
    const float* b1        = (const float*)d_in[4];
    const float* W2        = (const float*)d_in[5];
    const float* b2        = (const float*)d_in[6];
    const float* W3        = (const float*)d_in[7];
    const float* b3        = (const float*)d_in[8];
    const float* el_spread = (const float*)d_in[9];
    const float* sensors   = (const float*)d_in[10];
    float* out = (float*)d_out;

    char* ws = (char*)d_ws;
    _Float16* bfrag  = (_Float16*)(ws + OFF_BFRAG);
    float2*   posc   = (float2*)(ws + OFF_POSC);
    float*    part   = (float*)(ws + OFF_PART);
    float4*   edata2 = (float4*)(ws + OFF_EDATA2);
    int*      list   = (int*)(ws + OFF_LIST);
    int*      cnt    = (int*)(ws + OFF_CNT);

    hipMemsetAsync(cnt, 0, NBINS * sizeof(int), stream);

    k_fused<<<NG / 32, 256, 0, stream>>>(
        sim, zpos, mask, W1, b1, W2, b2, W3, b3, el_spread,
        edata2, cnt, list);

    k_prof<<<dim3(CCAP / 2, NBINS), 256, 0, stream>>>(
        edata2, cnt, list, bfrag, posc);

    k_main<<<dim3(NSB, NBINS, SPLIT), 256, 0, stream>>>(
        bfrag, posc, cnt, el_spread, sensors, part);

    k_reduce<<<dim3(NSB, NBINS), 256, 0, stream>>>((const float4*)part, out);
}